// Round 8
// baseline (278.026 us; speedup 1.0000x reference)
//
#include <hip/hip_runtime.h>
#include <hip/hip_fp16.h>

#define D     64
#define RPB   256            // rows per bucket (rowlocal = 8 bits, shift 17)
#define BCAP  4608           // capacity: mean 4096, sigma 64 -> +8 sigma slack
#define EPB   4096           // edges per phase-1 chunk (391 chunks)
#define NBMAX 400            // max buckets (N=100000 -> 391)
#define G     512            // grid: 2 blocks/CU co-resident (1024 slots >= 512)

typedef __attribute__((ext_vector_type(8))) _Float16 f16x8;
typedef __attribute__((ext_vector_type(4))) float    f32x4;

// ---------------------------------------------------------------------------
// Hand-rolled grid barrier (what cg::grid.sync() is in software, minus the
// cooperative-launch API that failed under graph capture in R5).
// Device-scope atomics + agent fences per G16. Counter used once per launch
// (no sense reversal); zeroed by the memset dispatch. Bounded spin: a broken
// barrier shows as absmax-fail, never a hang.
// ---------------------------------------------------------------------------
__device__ __forceinline__ void grid_barrier(int* ctr, int nblk) {
    __syncthreads();
    if (threadIdx.x == 0) {
        __threadfence();                                  // release: wbl2
        atomicAdd(ctr, 1);                                // device scope
        int guard = 0;
        while (__hip_atomic_load(ctr, __ATOMIC_RELAXED,
                                 __HIP_MEMORY_SCOPE_AGENT) < nblk) {
            __builtin_amdgcn_s_sleep(2);
            if (++guard > (1 << 22)) break;               // ~0.2s safety valve
        }
        __threadfence();                                  // acquire: inv
    }
    __syncthreads();
}

// ---------------------------------------------------------------------------
// Single fused kernel, 3 phases, 2 grid barriers. Phase math is byte-identical
// to the verified 160.7us pipeline (R2 widened K4). Phase 3 adds 2-row
// interleaving (counter-driven: K4 is latency-bound at reduced occupancy;
// sentinel row xh[N]=0 makes the pairing branch-free).
// ---------------------------------------------------------------------------
__global__ __launch_bounds__(512, 4) void gcn_fused(
    const int* __restrict__ ei, int E, int nb,
    const float* __restrict__ x, const float* __restrict__ W,
    int* __restrict__ cursor, int* __restrict__ bar,
    int* __restrict__ bbuf, int4* __restrict__ rowinfo,
    __half* __restrict__ xh, float4* __restrict__ out4, int N)
{
    __shared__ int   sh_sorted[BCAP];
    __shared__ int   sh_hist[RPB];
    __shared__ int   sh_curs[RPB];
    __shared__ float sh_dinv[RPB];
    __shared__ int   sh_w[4];
    __shared__ int   sh_h1[NBMAX];
    __shared__ int   sh_b1[NBMAX];
    int tid = threadIdx.x;

    // ---------------- phase 1: bucket scatter (391 chunks / 512 blocks) ----
    if (blockIdx.x == 0 && tid < D) xh[(size_t)N * D + tid] = __float2half(0.0f);

    for (int ch = blockIdx.x; ch * EPB < E; ch += G) {
        for (int i = tid; i < nb; i += 512) sh_h1[i] = 0;
        __syncthreads();
        int e0 = ch * EPB;
        int n  = min(EPB, E - e0);
        for (int idx = tid; idx < n; idx += 512)
            atomicAdd(&sh_h1[ei[e0 + idx] >> 8], 1);         // LDS atomic
        __syncthreads();
        for (int i = tid; i < nb; i += 512) {
            int c = sh_h1[i];
            sh_b1[i] = (c > 0) ? atomicAdd(&cursor[i], c) : 0;
            sh_h1[i] = 0;                                    // reuse as local cursor
        }
        __syncthreads();
        for (int idx = tid; idx < n; idx += 512) {
            int r = ei[e0 + idx];                            // L2-hot re-read
            int c = ei[E + e0 + idx];
            int b = r >> 8;
            int off = sh_b1[b] + atomicAdd(&sh_h1[b], 1);
            if (off < BCAP)
                bbuf[(size_t)b * BCAP + off] = ((r & (RPB - 1)) << 17) | c;
        }
        __syncthreads();
    }
    grid_barrier(&bar[0], G);

    // ---------------- phase 2: sort + rowinfo + linear (1 bucket/block) ----
    int lane = tid & 63;
    int wv   = tid >> 6;
    int r16  = lane & 15;
    int quad = lane >> 4;

    f16x8 Bf[4][2];
#pragma unroll
    for (int g = 0; g < 4; ++g)
#pragma unroll
        for (int s2 = 0; s2 < 2; ++s2) {
            const float4* wp = (const float4*)(W + (size_t)(16 * g + r16) * D + 32 * s2 + quad * 8);
            float4 w0 = wp[0], w1 = wp[1];
            f16x8 h;
            h[0] = (_Float16)w0.x; h[1] = (_Float16)w0.y;
            h[2] = (_Float16)w0.z; h[3] = (_Float16)w0.w;
            h[4] = (_Float16)w1.x; h[5] = (_Float16)w1.y;
            h[6] = (_Float16)w1.z; h[7] = (_Float16)w1.w;
            Bf[g][s2] = h;
        }

    for (int b = blockIdx.x; b < nb; b += G) {
        int cnt = min(cursor[b], BCAP);
        int* gbuf = bbuf + (size_t)b * BCAP;

        if (tid < RPB) sh_hist[tid] = 0;
        __syncthreads();

        for (int j = tid * 4; j < cnt; j += 2048) {          // int4 histogram
            int4 v = *(const int4*)(gbuf + j);
            atomicAdd(&sh_hist[(v.x >> 17) & 255], 1);
            if (j + 1 < cnt) atomicAdd(&sh_hist[(v.y >> 17) & 255], 1);
            if (j + 2 < cnt) atomicAdd(&sh_hist[(v.z >> 17) & 255], 1);
            if (j + 3 < cnt) atomicAdd(&sh_hist[(v.w >> 17) & 255], 1);
        }
        __syncthreads();

        int dv = 0, s = 0;
        if (tid < RPB) {
            dv = sh_hist[tid];
            s = dv;
#pragma unroll
            for (int off = 1; off < 64; off <<= 1) {
                int t = __shfl_up(s, off);
                if ((tid & 63) >= off) s += t;
            }
            if ((tid & 63) == 63) sh_w[tid >> 6] = s;
        }
        __syncthreads();
        if (tid < RPB) {
            int woff = 0;
#pragma unroll
            for (int i = 0; i < 3; ++i)
                if ((tid >> 6) > i) woff += sh_w[i];
            int excl = s + woff - dv;                        // exclusive prefix
            float di = (dv > 0) ? rsqrtf((float)dv) : 0.0f;
            sh_dinv[tid] = di;
            int r = (b << 8) + tid;
            if (r < N)
                rowinfo[r] = make_int4(b * BCAP + excl, dv, __float_as_int(di), 0);
            sh_curs[tid] = excl;
        }
        __syncthreads();

        for (int j = tid * 4; j < cnt; j += 2048) {          // int4 scatter
            int4 v = *(const int4*)(gbuf + j);
            sh_sorted[atomicAdd(&sh_curs[(v.x >> 17) & 255], 1)] = v.x;
            if (j + 1 < cnt) sh_sorted[atomicAdd(&sh_curs[(v.y >> 17) & 255], 1)] = v.y;
            if (j + 2 < cnt) sh_sorted[atomicAdd(&sh_curs[(v.z >> 17) & 255], 1)] = v.z;
            if (j + 3 < cnt) sh_sorted[atomicAdd(&sh_curs[(v.w >> 17) & 255], 1)] = v.w;
        }
        __syncthreads();

        int cnt4 = (cnt + 3) & ~3;
        for (int j = tid * 4; j < cnt4; j += 2048)           // int4 writeback
            *(int4*)(gbuf + j) = *(const int4*)(sh_sorted + j);

        for (int tl = wv; tl < 16; tl += 8) {                // 2 tiles per wave
            int r0 = (b << 8) + tl * 16;
            if (r0 >= N) break;
            int ra = min(r0 + r16, N - 1);
            const float4* xp = (const float4*)(x + (size_t)ra * D + quad * 8);
            float4 a0 = xp[0], a1 = xp[1], a2 = xp[8], a3 = xp[9];
            f16x8 A0, A1;
            A0[0] = (_Float16)a0.x; A0[1] = (_Float16)a0.y; A0[2] = (_Float16)a0.z; A0[3] = (_Float16)a0.w;
            A0[4] = (_Float16)a1.x; A0[5] = (_Float16)a1.y; A0[6] = (_Float16)a1.z; A0[7] = (_Float16)a1.w;
            A1[0] = (_Float16)a2.x; A1[1] = (_Float16)a2.y; A1[2] = (_Float16)a2.z; A1[3] = (_Float16)a2.w;
            A1[4] = (_Float16)a3.x; A1[5] = (_Float16)a3.y; A1[6] = (_Float16)a3.z; A1[7] = (_Float16)a3.w;

            f32x4 acc[4];
#pragma unroll
            for (int g = 0; g < 4; ++g) {
                f32x4 z = {0.f, 0.f, 0.f, 0.f};
                z = __builtin_amdgcn_mfma_f32_16x16x32_f16(A0, Bf[g][0], z, 0, 0, 0);
                acc[g] = __builtin_amdgcn_mfma_f32_16x16x32_f16(A1, Bf[g][1], z, 0, 0, 0);
            }

#pragma unroll
            for (int reg = 0; reg < 4; ++reg) {
                int rl = tl * 16 + quad * 4 + reg;
                int rr = (b << 8) + rl;
                if (rr < N) {
                    float dvr = sh_dinv[rl];
                    __half* op = xh + (size_t)rr * D + r16;
#pragma unroll
                    for (int g = 0; g < 4; ++g)
                        op[16 * g] = __float2half(dvr * acc[g][reg]);
                }
            }
        }
        __syncthreads();
    }
    grid_barrier(&bar[1], G);

    // ---------------- phase 3: SpMM, 2-row-interleaved widened gathers ------
    const float2* xhq = (const float2*)xh;
    int nw  = G * 8;                  // 4096 waves
    int wid = blockIdx.x * 8 + (tid >> 6);
    int c   = tid & 63;
    int sub = c >> 4;                 // edge slot 0..3
    int f   = c & 15;                 // feature-quad index (8 B)

    for (int r = wid; r < N; r += 2 * nw) {
        int rB = r + nw;
        int4 riA = rowinfo[r];
        int4 riB = (rB < N) ? rowinfo[rB] : make_int4(0, 0, 0, 0);
        int cnA = (c < min(riA.y, 64)) ? (bbuf[riA.x + c] & 0x1FFFF) : N;
        int cnB = (rB < N && c < min(riB.y, 64)) ? (bbuf[riB.x + c] & 0x1FFFF) : N;

        float dA = __int_as_float(riA.z), dB = __int_as_float(riB.z);
        float aA0 = 0.f, aA1 = 0.f, aA2 = 0.f, aA3 = 0.f;
        float aB0 = 0.f, aB1 = 0.f, aB2 = 0.f, aB3 = 0.f;

        int nA = (min(riA.y, 64) + 15) & ~15;
        int nB = (min(riB.y, 64) + 15) & ~15;
        int nmax = max(nA, nB);
        for (int k = 0; k < nmax; k += 16) {
            // 8 independent gathers in flight (4 per row); sentinel lanes
            // (>= deg) carry col N -> zero row, accumulate 0, branch-free.
            int eA0 = __shfl(cnA, k +  0 + sub);
            int eA1 = __shfl(cnA, k +  4 + sub);
            int eA2 = __shfl(cnA, k +  8 + sub);
            int eA3 = __shfl(cnA, k + 12 + sub);
            int eB0 = __shfl(cnB, k +  0 + sub);
            int eB1 = __shfl(cnB, k +  4 + sub);
            int eB2 = __shfl(cnB, k +  8 + sub);
            int eB3 = __shfl(cnB, k + 12 + sub);
            float2 qa0 = xhq[(size_t)eA0 * 16 + f];
            float2 qa1 = xhq[(size_t)eA1 * 16 + f];
            float2 qa2 = xhq[(size_t)eA2 * 16 + f];
            float2 qa3 = xhq[(size_t)eA3 * 16 + f];
            float2 qb0 = xhq[(size_t)eB0 * 16 + f];
            float2 qb1 = xhq[(size_t)eB1 * 16 + f];
            float2 qb2 = xhq[(size_t)eB2 * 16 + f];
            float2 qb3 = xhq[(size_t)eB3 * 16 + f];
            float2 u;
            u = __half22float2(__builtin_bit_cast(__half2, qa0.x)); aA0 += u.x; aA1 += u.y;
            u = __half22float2(__builtin_bit_cast(__half2, qa0.y)); aA2 += u.x; aA3 += u.y;
            u = __half22float2(__builtin_bit_cast(__half2, qa1.x)); aA0 += u.x; aA1 += u.y;
            u = __half22float2(__builtin_bit_cast(__half2, qa1.y)); aA2 += u.x; aA3 += u.y;
            u = __half22float2(__builtin_bit_cast(__half2, qa2.x)); aA0 += u.x; aA1 += u.y;
            u = __half22float2(__builtin_bit_cast(__half2, qa2.y)); aA2 += u.x; aA3 += u.y;
            u = __half22float2(__builtin_bit_cast(__half2, qa3.x)); aA0 += u.x; aA1 += u.y;
            u = __half22float2(__builtin_bit_cast(__half2, qa3.y)); aA2 += u.x; aA3 += u.y;
            u = __half22float2(__builtin_bit_cast(__half2, qb0.x)); aB0 += u.x; aB1 += u.y;
            u = __half22float2(__builtin_bit_cast(__half2, qb0.y)); aB2 += u.x; aB3 += u.y;
            u = __half22float2(__builtin_bit_cast(__half2, qb1.x)); aB0 += u.x; aB1 += u.y;
            u = __half22float2(__builtin_bit_cast(__half2, qb1.y)); aB2 += u.x; aB3 += u.y;
            u = __half22float2(__builtin_bit_cast(__half2, qb2.x)); aB0 += u.x; aB1 += u.y;
            u = __half22float2(__builtin_bit_cast(__half2, qb2.y)); aB2 += u.x; aB3 += u.y;
            u = __half22float2(__builtin_bit_cast(__half2, qb3.x)); aB0 += u.x; aB1 += u.y;
            u = __half22float2(__builtin_bit_cast(__half2, qb3.y)); aB2 += u.x; aB3 += u.y;
        }
        // rare deg>64 tails, per row
        for (int j0 = 64; j0 < riA.y; j0 += 64) {
            int nn = min(riA.y - j0, 64);
            int cnx = (c < nn) ? (bbuf[riA.x + j0 + c] & 0x1FFFF) : N;
            int m16 = (nn + 15) & ~15;
            for (int k = 0; k < m16; k += 16) {
                int e0 = __shfl(cnx, k +  0 + sub);
                int e1 = __shfl(cnx, k +  4 + sub);
                int e2 = __shfl(cnx, k +  8 + sub);
                int e3 = __shfl(cnx, k + 12 + sub);
                float2 q0 = xhq[(size_t)e0 * 16 + f];
                float2 q1 = xhq[(size_t)e1 * 16 + f];
                float2 q2 = xhq[(size_t)e2 * 16 + f];
                float2 q3 = xhq[(size_t)e3 * 16 + f];
                float2 u;
                u = __half22float2(__builtin_bit_cast(__half2, q0.x)); aA0 += u.x; aA1 += u.y;
                u = __half22float2(__builtin_bit_cast(__half2, q0.y)); aA2 += u.x; aA3 += u.y;
                u = __half22float2(__builtin_bit_cast(__half2, q1.x)); aA0 += u.x; aA1 += u.y;
                u = __half22float2(__builtin_bit_cast(__half2, q1.y)); aA2 += u.x; aA3 += u.y;
                u = __half22float2(__builtin_bit_cast(__half2, q2.x)); aA0 += u.x; aA1 += u.y;
                u = __half22float2(__builtin_bit_cast(__half2, q2.y)); aA2 += u.x; aA3 += u.y;
                u = __half22float2(__builtin_bit_cast(__half2, q3.x)); aA0 += u.x; aA1 += u.y;
                u = __half22float2(__builtin_bit_cast(__half2, q3.y)); aA2 += u.x; aA3 += u.y;
            }
        }
        for (int j0 = 64; j0 < riB.y; j0 += 64) {
            int nn = min(riB.y - j0, 64);
            int cnx = (c < nn) ? (bbuf[riB.x + j0 + c] & 0x1FFFF) : N;
            int m16 = (nn + 15) & ~15;
            for (int k = 0; k < m16; k += 16) {
                int e0 = __shfl(cnx, k +  0 + sub);
                int e1 = __shfl(cnx, k +  4 + sub);
                int e2 = __shfl(cnx, k +  8 + sub);
                int e3 = __shfl(cnx, k + 12 + sub);
                float2 q0 = xhq[(size_t)e0 * 16 + f];
                float2 q1 = xhq[(size_t)e1 * 16 + f];
                float2 q2 = xhq[(size_t)e2 * 16 + f];
                float2 q3 = xhq[(size_t)e3 * 16 + f];
                float2 u;
                u = __half22float2(__builtin_bit_cast(__half2, q0.x)); aB0 += u.x; aB1 += u.y;
                u = __half22float2(__builtin_bit_cast(__half2, q0.y)); aB2 += u.x; aB3 += u.y;
                u = __half22float2(__builtin_bit_cast(__half2, q1.x)); aB0 += u.x; aB1 += u.y;
                u = __half22float2(__builtin_bit_cast(__half2, q1.y)); aB2 += u.x; aB3 += u.y;
                u = __half22float2(__builtin_bit_cast(__half2, q2.x)); aB0 += u.x; aB1 += u.y;
                u = __half22float2(__builtin_bit_cast(__half2, q2.y)); aB2 += u.x; aB3 += u.y;
                u = __half22float2(__builtin_bit_cast(__half2, q3.x)); aB0 += u.x; aB1 += u.y;
                u = __half22float2(__builtin_bit_cast(__half2, q3.y)); aB2 += u.x; aB3 += u.y;
            }
        }

        // butterfly over lane bits 4 and 5, both rows
        float tA0 = aA0 + __shfl(aA0, c ^ 16);
        float tA1 = aA1 + __shfl(aA1, c ^ 16);
        float tA2 = aA2 + __shfl(aA2, c ^ 16);
        float tA3 = aA3 + __shfl(aA3, c ^ 16);
        float tB0 = aB0 + __shfl(aB0, c ^ 16);
        float tB1 = aB1 + __shfl(aB1, c ^ 16);
        float tB2 = aB2 + __shfl(aB2, c ^ 16);
        float tB3 = aB3 + __shfl(aB3, c ^ 16);
        float sA0 = tA0 + __shfl(tA0, c ^ 32);
        float sA1 = tA1 + __shfl(tA1, c ^ 32);
        float sA2 = tA2 + __shfl(tA2, c ^ 32);
        float sA3 = tA3 + __shfl(tA3, c ^ 32);
        float sB0 = tB0 + __shfl(tB0, c ^ 32);
        float sB1 = tB1 + __shfl(tB1, c ^ 32);
        float sB2 = tB2 + __shfl(tB2, c ^ 32);
        float sB3 = tB3 + __shfl(tB3, c ^ 32);
        if (sub == 0) {
            f32x4 resA = {dA * sA0, dA * sA1, dA * sA2, dA * sA3};
            __builtin_nontemporal_store(resA, (f32x4*)&out4[(size_t)r * 16 + f]);
            if (rB < N) {
                f32x4 resB = {dB * sB0, dB * sB1, dB * sB2, dB * sB3};
                __builtin_nontemporal_store(resB, (f32x4*)&out4[(size_t)rB * 16 + f]);
            }
        }
    }
}

extern "C" void kernel_launch(void* const* d_in, const int* in_sizes, int n_in,
                              void* d_out, int out_size, void* d_ws, size_t ws_size,
                              hipStream_t stream) {
    const int*   ei = (const int*)d_in[0];   // (2,E) flat: [0..E) rows, [E..2E) cols
    const float* x  = (const float*)d_in[1]; // (N,64)
    const float* W  = (const float*)d_in[2]; // (64,64)
    float4* out = (float4*)d_out;            // (N,64)

    int E  = in_sizes[0] / 2;
    int N  = in_sizes[1] / D;
    int nb = (N + RPB - 1) / RPB;            // 391 for N=100000 (<= NBMAX)

    // Workspace layout (256 B aligned slices)
    char* p = (char*)d_ws;
    size_t off = 0;
    auto take = [&](size_t bytes) -> char* {
        char* cur = p + off;
        off = (off + bytes + 255) & ~(size_t)255;
        return cur;
    };
    int*    zr      = (int*)take(2048);      // [0..nb) cursor, [448..450) barriers
    int*    cursor  = zr;
    int*    bar     = zr + 448;
    int4*   rowinfo = (int4*)take((size_t)N * 16);
    int*    bbuf    = (int*)take((size_t)nb * BCAP * 4);
    __half* xh      = (__half*)take((size_t)(N + 1) * D * 2);  // +1 zero sentinel row
    (void)ws_size;

    hipMemsetAsync(zr, 0, 2048, stream);     // cursor + barrier counters

    void* args[] = {
        (void*)&ei, (void*)&E, (void*)&nb, (void*)&x, (void*)&W,
        (void*)&cursor, (void*)&bar, (void*)&bbuf, (void*)&rowinfo,
        (void*)&xh, (void*)&out, (void*)&N
    };
    hipLaunchKernel((const void*)gcn_fused, dim3(G), dim3(512), args, 0, stream);
}

// Round 9
// 170.681 us; speedup vs baseline: 1.6289x; 1.6289x over previous
//
#include <hip/hip_runtime.h>
#include <hip/hip_fp16.h>

#define D     64
#define RPB   256            // rows per bucket (rowlocal = 8 bits, shift 17)
#define BCAP  4608           // capacity: mean 4096, sigma 64 -> +8 sigma slack
#define EPB   4096           // edges per bucket_kernel block (391 blocks x 8 waves)
#define NBMAX 400            // max buckets (N=100000 -> 391)

typedef __attribute__((ext_vector_type(8))) _Float16 f16x8;
typedef __attribute__((ext_vector_type(4))) float    f32x4;

// ---------------------------------------------------------------------------
// K1: coarse bucket scatter (verified, unchanged).
// ---------------------------------------------------------------------------
__global__ __launch_bounds__(512) void bucket_kernel(const int* __restrict__ ei, int E,
                                                     int nb,
                                                     int* __restrict__ cursor,
                                                     int* __restrict__ bbuf) {
    __shared__ int hist[NBMAX];
    __shared__ int base_l[NBMAX];
    int tid = threadIdx.x;

    for (int i = tid; i < nb; i += 512) hist[i] = 0;
    __syncthreads();

    int e0 = blockIdx.x * EPB;
    int n  = min(EPB, E - e0);

    for (int idx = tid; idx < n; idx += 512)
        atomicAdd(&hist[ei[e0 + idx] >> 8], 1);          // LDS atomic
    __syncthreads();

    for (int i = tid; i < nb; i += 512) {
        int c = hist[i];
        base_l[i] = (c > 0) ? atomicAdd(&cursor[i], c) : 0;  // 1 global atomic/(block,bucket)
        hist[i] = 0;                                     // reuse as local cursor
    }
    __syncthreads();

    for (int idx = tid; idx < n; idx += 512) {
        int r = ei[e0 + idx];                            // L2-hot re-read
        int c = ei[E + e0 + idx];
        int b = r >> 8;
        int off = base_l[b] + atomicAdd(&hist[b], 1);
        if (off < BCAP)                                  // impossible-overflow guard
            bbuf[(size_t)b * BCAP + off] = ((r & (RPB - 1)) << 17) | c;
    }
}

// ---------------------------------------------------------------------------
// K2+K3 fused (verified at 160.7/161.5us, unchanged).
// ---------------------------------------------------------------------------
__global__ __launch_bounds__(512) void sort_linear_kernel(const int* __restrict__ cursor,
                                                          int* __restrict__ bbuf,
                                                          const float* __restrict__ x,
                                                          const float* __restrict__ W,
                                                          int4* __restrict__ rowinfo,
                                                          __half* __restrict__ xh, int N) {
    __shared__ int   sorted[BCAP];
    __shared__ int   hist[RPB];
    __shared__ int   curs[RPB];
    __shared__ float sdinv[RPB];
    __shared__ int   wsum[4];
    int b = blockIdx.x, tid = threadIdx.x;
    int cnt = min(cursor[b], BCAP);
    int* gbuf = bbuf + (size_t)b * BCAP;

    if (tid < RPB) hist[tid] = 0;
    __syncthreads();

    // histogram pass, int4-vectorized
    for (int j = tid * 4; j < cnt; j += 2048) {
        int4 v = *(const int4*)(gbuf + j);
        atomicAdd(&hist[(v.x >> 17) & 255], 1);
        if (j + 1 < cnt) atomicAdd(&hist[(v.y >> 17) & 255], 1);
        if (j + 2 < cnt) atomicAdd(&hist[(v.z >> 17) & 255], 1);
        if (j + 3 < cnt) atomicAdd(&hist[(v.w >> 17) & 255], 1);
    }
    __syncthreads();

    // exclusive prefix over 256 bins: waves 0-3 scan 64 bins each via shfl
    int dv = 0, s = 0;
    if (tid < RPB) {
        dv = hist[tid];
        s = dv;
#pragma unroll
        for (int off = 1; off < 64; off <<= 1) {
            int t = __shfl_up(s, off);
            if ((tid & 63) >= off) s += t;
        }
        if ((tid & 63) == 63) wsum[tid >> 6] = s;
    }
    __syncthreads();
    if (tid < RPB) {
        int woff = 0;
#pragma unroll
        for (int i = 0; i < 3; ++i)
            if ((tid >> 6) > i) woff += wsum[i];
        int excl = s + woff - dv;                        // exclusive prefix
        float di = (dv > 0) ? rsqrtf((float)dv) : 0.0f;
        sdinv[tid] = di;
        int r = (b << 8) + tid;
        if (r < N)
            rowinfo[r] = make_int4(b * BCAP + excl, dv, __float_as_int(di), 0);
        curs[tid] = excl;
    }
    __syncthreads();

    // scatter into sorted[], int4-vectorized reads
    for (int j = tid * 4; j < cnt; j += 2048) {
        int4 v = *(const int4*)(gbuf + j);
        sorted[atomicAdd(&curs[(v.x >> 17) & 255], 1)] = v.x;
        if (j + 1 < cnt) sorted[atomicAdd(&curs[(v.y >> 17) & 255], 1)] = v.y;
        if (j + 2 < cnt) sorted[atomicAdd(&curs[(v.z >> 17) & 255], 1)] = v.z;
        if (j + 3 < cnt) sorted[atomicAdd(&curs[(v.w >> 17) & 255], 1)] = v.w;
    }
    __syncthreads();

    // write back sorted bucket, int4 stores
    int cnt4 = (cnt + 3) & ~3;
    for (int j = tid * 4; j < cnt4; j += 2048)
        *(int4*)(gbuf + j) = *(const int4*)(sorted + j);

    // ---------------- linear phase (block's own 16 row-tiles) ----------------
    int lane = tid & 63;
    int wv   = tid >> 6;    // 0..7
    int r16  = lane & 15;
    int quad = lane >> 4;

    if (b == 0 && tid < D) xh[(size_t)N * D + tid] = __float2half(0.0f);

    // B fragments: Bf[g][s] = W[16g + r16][32s + quad*8 + j], j=0..7
    f16x8 Bf[4][2];
#pragma unroll
    for (int g = 0; g < 4; ++g)
#pragma unroll
        for (int s2 = 0; s2 < 2; ++s2) {
            const float4* wp = (const float4*)(W + (size_t)(16 * g + r16) * D + 32 * s2 + quad * 8);
            float4 w0 = wp[0], w1 = wp[1];
            f16x8 h;
            h[0] = (_Float16)w0.x; h[1] = (_Float16)w0.y;
            h[2] = (_Float16)w0.z; h[3] = (_Float16)w0.w;
            h[4] = (_Float16)w1.x; h[5] = (_Float16)w1.y;
            h[6] = (_Float16)w1.z; h[7] = (_Float16)w1.w;
            Bf[g][s2] = h;
        }

    for (int tl = wv; tl < 16; tl += 8) {                // 2 tiles per wave
        int r0 = (b << 8) + tl * 16;
        if (r0 >= N) break;                              // r0 wave-uniform
        int ra = min(r0 + r16, N - 1);
        const float4* xp = (const float4*)(x + (size_t)ra * D + quad * 8);
        float4 a0 = xp[0], a1 = xp[1], a2 = xp[8], a3 = xp[9];
        f16x8 A0, A1;
        A0[0] = (_Float16)a0.x; A0[1] = (_Float16)a0.y; A0[2] = (_Float16)a0.z; A0[3] = (_Float16)a0.w;
        A0[4] = (_Float16)a1.x; A0[5] = (_Float16)a1.y; A0[6] = (_Float16)a1.z; A0[7] = (_Float16)a1.w;
        A1[0] = (_Float16)a2.x; A1[1] = (_Float16)a2.y; A1[2] = (_Float16)a2.z; A1[3] = (_Float16)a2.w;
        A1[4] = (_Float16)a3.x; A1[5] = (_Float16)a3.y; A1[6] = (_Float16)a3.z; A1[7] = (_Float16)a3.w;

        f32x4 acc[4];
#pragma unroll
        for (int g = 0; g < 4; ++g) {
            f32x4 z = {0.f, 0.f, 0.f, 0.f};
            z = __builtin_amdgcn_mfma_f32_16x16x32_f16(A0, Bf[g][0], z, 0, 0, 0);
            acc[g] = __builtin_amdgcn_mfma_f32_16x16x32_f16(A1, Bf[g][1], z, 0, 0, 0);
        }

#pragma unroll
        for (int reg = 0; reg < 4; ++reg) {
            int rl = tl * 16 + quad * 4 + reg;           // local row 0..255
            int rr = (b << 8) + rl;
            if (rr < N) {
                float dvr = sdinv[rl];
                __half* op = xh + (size_t)rr * D + r16;
#pragma unroll
                for (int g = 0; g < 4; ++g)
                    op[16 * g] = __float2half(dvr * acc[g][reg]);
            }
        }
    }
}

// ---------------------------------------------------------------------------
// K4 v3: widened gathers (8 B/lane x 16 lanes/row) + PAIR-INTERLEAVED rows.
//     Counter-driven (R6/R8): K4 is L2-miss latency-bound (FETCH 79MB vs
//     12.8MB working set, 1.35 TB/s effective). Each wave now works rows
//     (r, r+stride) concurrently -> 8 gathers in flight (2x MLP), with the
//     verified 2-ahead pipeline at pair granularity: rowinfo 2 pairs ahead,
//     col vectors 1 pair ahead. Sentinel row xh[N]=0 makes unequal pair
//     degrees branch-free (extra gathers hit the zero row, add 0).
// ---------------------------------------------------------------------------
__global__ __launch_bounds__(256) void spmm_kernel(const int4* __restrict__ rowinfo,
                                                   const int* __restrict__ bbuf,
                                                   const float2* __restrict__ xhq,
                                                   float4* __restrict__ out4,
                                                   int N, int stride) {
    int wid = (blockIdx.x * 256 + threadIdx.x) >> 6;
    int c   = threadIdx.x & 63;
    int sub = c >> 4;   // edge slot 0..3
    int f   = c & 15;   // feature-quad index (8 B)

    int r0 = wid;
    if (r0 >= N) return;
    int pstep = 2 * stride;
    const int4 zri = make_int4(0, 0, 0, 0);

    // current pair (A=r, B=r+stride) and next pair's rowinfo
    int4 riA0 = rowinfo[r0];
    int4 riB0 = (r0 + stride < N) ? rowinfo[r0 + stride] : zri;
    int  rn   = r0 + pstep;
    int4 riA1 = (rn < N) ? rowinfo[rn] : zri;
    int4 riB1 = (rn + stride < N) ? rowinfo[rn + stride] : zri;
    int  cnA0 = (c < min(riA0.y, 64)) ? (bbuf[riA0.x + c] & 0x1FFFF) : N;
    int  cnB0 = (c < min(riB0.y, 64)) ? (bbuf[riB0.x + c] & 0x1FFFF) : N;

    for (int r = r0; r < N; r += pstep) {
        int rB  = r + stride;
        int rn1 = r + pstep;
        int rn2 = r + 2 * pstep;
        // prefetch rowinfo two pairs ahead, cols one pair ahead
        int4 riA2 = (rn2 < N) ? rowinfo[rn2] : zri;
        int4 riB2 = (rn2 + stride < N) ? rowinfo[rn2 + stride] : zri;
        int  cnA1 = (rn1 < N && c < min(riA1.y, 64)) ? (bbuf[riA1.x + c] & 0x1FFFF) : N;
        int  cnB1 = (c < min(riB1.y, 64)) ? (bbuf[riB1.x + c] & 0x1FFFF) : N;

        float dA = __int_as_float(riA0.z), dB = __int_as_float(riB0.z);
        float aA0 = 0.f, aA1 = 0.f, aA2 = 0.f, aA3 = 0.f;
        float aB0 = 0.f, aB1 = 0.f, aB2 = 0.f, aB3 = 0.f;

        int nA = (min(riA0.y, 64) + 15) & ~15;
        int nB = (min(riB0.y, 64) + 15) & ~15;
        int nmax = max(nA, nB);
        for (int k = 0; k < nmax; k += 16) {
            int eA0 = __shfl(cnA0, k +  0 + sub);
            int eA1 = __shfl(cnA0, k +  4 + sub);
            int eA2 = __shfl(cnA0, k +  8 + sub);
            int eA3 = __shfl(cnA0, k + 12 + sub);
            int eB0 = __shfl(cnB0, k +  0 + sub);
            int eB1 = __shfl(cnB0, k +  4 + sub);
            int eB2 = __shfl(cnB0, k +  8 + sub);
            int eB3 = __shfl(cnB0, k + 12 + sub);
            float2 qa0 = xhq[(size_t)eA0 * 16 + f];
            float2 qa1 = xhq[(size_t)eA1 * 16 + f];
            float2 qa2 = xhq[(size_t)eA2 * 16 + f];
            float2 qa3 = xhq[(size_t)eA3 * 16 + f];
            float2 qb0 = xhq[(size_t)eB0 * 16 + f];
            float2 qb1 = xhq[(size_t)eB1 * 16 + f];
            float2 qb2 = xhq[(size_t)eB2 * 16 + f];
            float2 qb3 = xhq[(size_t)eB3 * 16 + f];
            float2 u;
            u = __half22float2(__builtin_bit_cast(__half2, qa0.x)); aA0 += u.x; aA1 += u.y;
            u = __half22float2(__builtin_bit_cast(__half2, qa0.y)); aA2 += u.x; aA3 += u.y;
            u = __half22float2(__builtin_bit_cast(__half2, qa1.x)); aA0 += u.x; aA1 += u.y;
            u = __half22float2(__builtin_bit_cast(__half2, qa1.y)); aA2 += u.x; aA3 += u.y;
            u = __half22float2(__builtin_bit_cast(__half2, qa2.x)); aA0 += u.x; aA1 += u.y;
            u = __half22float2(__builtin_bit_cast(__half2, qa2.y)); aA2 += u.x; aA3 += u.y;
            u = __half22float2(__builtin_bit_cast(__half2, qa3.x)); aA0 += u.x; aA1 += u.y;
            u = __half22float2(__builtin_bit_cast(__half2, qa3.y)); aA2 += u.x; aA3 += u.y;
            u = __half22float2(__builtin_bit_cast(__half2, qb0.x)); aB0 += u.x; aB1 += u.y;
            u = __half22float2(__builtin_bit_cast(__half2, qb0.y)); aB2 += u.x; aB3 += u.y;
            u = __half22float2(__builtin_bit_cast(__half2, qb1.x)); aB0 += u.x; aB1 += u.y;
            u = __half22float2(__builtin_bit_cast(__half2, qb1.y)); aB2 += u.x; aB3 += u.y;
            u = __half22float2(__builtin_bit_cast(__half2, qb2.x)); aB0 += u.x; aB1 += u.y;
            u = __half22float2(__builtin_bit_cast(__half2, qb2.y)); aB2 += u.x; aB3 += u.y;
            u = __half22float2(__builtin_bit_cast(__half2, qb3.x)); aB0 += u.x; aB1 += u.y;
            u = __half22float2(__builtin_bit_cast(__half2, qb3.y)); aB2 += u.x; aB3 += u.y;
        }
        // rare deg>64 tails, per row
        for (int j0 = 64; j0 < riA0.y; j0 += 64) {
            int nn = min(riA0.y - j0, 64);
            int cnx = (c < nn) ? (bbuf[riA0.x + j0 + c] & 0x1FFFF) : N;
            int m16 = (nn + 15) & ~15;
            for (int k = 0; k < m16; k += 16) {
                int e0 = __shfl(cnx, k +  0 + sub);
                int e1 = __shfl(cnx, k +  4 + sub);
                int e2 = __shfl(cnx, k +  8 + sub);
                int e3 = __shfl(cnx, k + 12 + sub);
                float2 q0 = xhq[(size_t)e0 * 16 + f];
                float2 q1 = xhq[(size_t)e1 * 16 + f];
                float2 q2 = xhq[(size_t)e2 * 16 + f];
                float2 q3 = xhq[(size_t)e3 * 16 + f];
                float2 u;
                u = __half22float2(__builtin_bit_cast(__half2, q0.x)); aA0 += u.x; aA1 += u.y;
                u = __half22float2(__builtin_bit_cast(__half2, q0.y)); aA2 += u.x; aA3 += u.y;
                u = __half22float2(__builtin_bit_cast(__half2, q1.x)); aA0 += u.x; aA1 += u.y;
                u = __half22float2(__builtin_bit_cast(__half2, q1.y)); aA2 += u.x; aA3 += u.y;
                u = __half22float2(__builtin_bit_cast(__half2, q2.x)); aA0 += u.x; aA1 += u.y;
                u = __half22float2(__builtin_bit_cast(__half2, q2.y)); aA2 += u.x; aA3 += u.y;
                u = __half22float2(__builtin_bit_cast(__half2, q3.x)); aA0 += u.x; aA1 += u.y;
                u = __half22float2(__builtin_bit_cast(__half2, q3.y)); aA2 += u.x; aA3 += u.y;
            }
        }
        for (int j0 = 64; j0 < riB0.y; j0 += 64) {
            int nn = min(riB0.y - j0, 64);
            int cnx = (c < nn) ? (bbuf[riB0.x + j0 + c] & 0x1FFFF) : N;
            int m16 = (nn + 15) & ~15;
            for (int k = 0; k < m16; k += 16) {
                int e0 = __shfl(cnx, k +  0 + sub);
                int e1 = __shfl(cnx, k +  4 + sub);
                int e2 = __shfl(cnx, k +  8 + sub);
                int e3 = __shfl(cnx, k + 12 + sub);
                float2 q0 = xhq[(size_t)e0 * 16 + f];
                float2 q1 = xhq[(size_t)e1 * 16 + f];
                float2 q2 = xhq[(size_t)e2 * 16 + f];
                float2 q3 = xhq[(size_t)e3 * 16 + f];
                float2 u;
                u = __half22float2(__builtin_bit_cast(__half2, q0.x)); aB0 += u.x; aB1 += u.y;
                u = __half22float2(__builtin_bit_cast(__half2, q0.y)); aB2 += u.x; aB3 += u.y;
                u = __half22float2(__builtin_bit_cast(__half2, q1.x)); aB0 += u.x; aB1 += u.y;
                u = __half22float2(__builtin_bit_cast(__half2, q1.y)); aB2 += u.x; aB3 += u.y;
                u = __half22float2(__builtin_bit_cast(__half2, q2.x)); aB0 += u.x; aB1 += u.y;
                u = __half22float2(__builtin_bit_cast(__half2, q2.y)); aB2 += u.x; aB3 += u.y;
                u = __half22float2(__builtin_bit_cast(__half2, q3.x)); aB0 += u.x; aB1 += u.y;
                u = __half22float2(__builtin_bit_cast(__half2, q3.y)); aB2 += u.x; aB3 += u.y;
            }
        }

        // butterfly over lane bits 4 and 5, both rows
        float tA0 = aA0 + __shfl(aA0, c ^ 16);
        float tA1 = aA1 + __shfl(aA1, c ^ 16);
        float tA2 = aA2 + __shfl(aA2, c ^ 16);
        float tA3 = aA3 + __shfl(aA3, c ^ 16);
        float tB0 = aB0 + __shfl(aB0, c ^ 16);
        float tB1 = aB1 + __shfl(aB1, c ^ 16);
        float tB2 = aB2 + __shfl(aB2, c ^ 16);
        float tB3 = aB3 + __shfl(aB3, c ^ 16);
        float sA0 = tA0 + __shfl(tA0, c ^ 32);
        float sA1 = tA1 + __shfl(tA1, c ^ 32);
        float sA2 = tA2 + __shfl(tA2, c ^ 32);
        float sA3 = tA3 + __shfl(tA3, c ^ 32);
        float sB0 = tB0 + __shfl(tB0, c ^ 32);
        float sB1 = tB1 + __shfl(tB1, c ^ 32);
        float sB2 = tB2 + __shfl(tB2, c ^ 32);
        float sB3 = tB3 + __shfl(tB3, c ^ 32);
        if (sub == 0) {
            f32x4 resA = {dA * sA0, dA * sA1, dA * sA2, dA * sA3};
            __builtin_nontemporal_store(resA, (f32x4*)&out4[(size_t)r * 16 + f]);
            if (rB < N) {
                f32x4 resB = {dB * sB0, dB * sB1, dB * sB2, dB * sB3};
                __builtin_nontemporal_store(resB, (f32x4*)&out4[(size_t)rB * 16 + f]);
            }
        }
        riA0 = riA1; riB0 = riB1; riA1 = riA2; riB1 = riB2;
        cnA0 = cnA1; cnB0 = cnB1;
    }
}

extern "C" void kernel_launch(void* const* d_in, const int* in_sizes, int n_in,
                              void* d_out, int out_size, void* d_ws, size_t ws_size,
                              hipStream_t stream) {
    const int*   ei = (const int*)d_in[0];   // (2,E) flat: [0..E) rows, [E..2E) cols
    const float* x  = (const float*)d_in[1]; // (N,64)
    const float* W  = (const float*)d_in[2]; // (64,64)
    float* out = (float*)d_out;              // (N,64)

    int E  = in_sizes[0] / 2;
    int N  = in_sizes[1] / D;
    int nb = (N + RPB - 1) / RPB;            // 391 for N=100000 (<= NBMAX)

    // Workspace layout (256 B aligned slices) — ~21 MB total
    char* p = (char*)d_ws;
    size_t off = 0;
    auto take = [&](size_t bytes) -> char* {
        char* cur = p + off;
        off = (off + bytes + 255) & ~(size_t)255;
        return cur;
    };
    int4*   rowinfo = (int4*)take((size_t)N * 16);
    int*    cursor  = (int*)take((size_t)nb * 4);
    int*    bbuf    = (int*)take((size_t)nb * BCAP * 4);
    __half* xh      = (__half*)take((size_t)(N + 1) * D * 2);  // +1 zero sentinel row
    (void)ws_size;

    hipMemsetAsync(cursor, 0, (size_t)nb * 4, stream);

    bucket_kernel<<<(E + EPB - 1) / EPB, 512, 0, stream>>>(ei, E, nb, cursor, bbuf);
    sort_linear_kernel<<<nb, 512, 0, stream>>>(cursor, bbuf, x, W, rowinfo, xh, N);

    int spmm_blocks = 3072;                  // 12288 waves; pairs -> ~4 iters/wave
    spmm_kernel<<<spmm_blocks, 256, 0, stream>>>(rowinfo, bbuf, (const float2*)xh,
                                                 (float4*)out, N, spmm_blocks * 4);
}